// Round 4
// baseline (636.661 us; speedup 1.0000x reference)
//
#include <hip/hip_runtime.h>

typedef unsigned short u16;
typedef unsigned int u32;
using bf16x8 = __attribute__((ext_vector_type(8))) __bf16;
using f32x4  = __attribute__((ext_vector_type(4))) float;

#define T_TOK 4096
#define DIMD  1024
#define HIDN  2048
#define NEXP  8

// ---- workspace layout (bytes) ----
#define OFF_CNT  0                            // int[8]
#define OFF_TCNT 64                           // int[4096] (memset with cnt)
#define OFF_TOK  16448                        // int[8][4096]
#define OFF_WGT  (OFF_TOK + NEXP*T_TOK*4)     // float[8][4096]
#define OFF_T2S  (OFF_WGT + NEXP*T_TOK*4)     // int[4096][2]
#define OFF_XB   (1<<20)                      // bf16[4096][1024]
#define SZ_XB    (T_TOK*DIMD*2)
#define OFF_W1T  (OFF_XB + SZ_XB)             // bf16 [E][N][K]
#define SZ_W     (NEXP*DIMD*HIDN*2)
#define OFF_W3T  (OFF_W1T + SZ_W)
#define OFF_W2T  (OFF_W3T + SZ_W)
#define OFF_H    (OFF_W2T + SZ_W)             // bf16[8192][2048]
#define OFF_OS   OFF_W1T                      // fp32[8192][1024] ALIASES W1T (dead after gemm1)

__device__ __forceinline__ u16 f2bf(float f) {
    u32 u = __float_as_uint(f);
    u32 r = (u + 0x7fff + ((u >> 16) & 1)) >> 16;
    return (u16)r;
}

__device__ __forceinline__ void gl2lds16(const void* g, void* l) {
    __builtin_amdgcn_global_load_lds(
        (__attribute__((address_space(1))) void*)(g),
        (__attribute__((address_space(3))) void*)(l),
        16, 0, 0);
}

// swizzled LDS frag read (tile rows of 64 bf16; block b of row r at b ^ (r&7))
__device__ __forceinline__ bf16x8 ldfrag(const u16* base, int r, int s, int q) {
    int idx = r * 64 + ((((s << 2) | q) ^ (r & 7)) << 3);
    union { uint4 u; bf16x8 b; } c;
    c.u = *(const uint4*)(base + idx);
    return c.b;
}

// direct global frag read: 8 contiguous bf16 at rowp[k]
__device__ __forceinline__ bf16x8 ldfragG(const u16* rowp, int k) {
    union { uint4 u; bf16x8 b; } c;
    c.u = *(const uint4*)(rowp + k);
    return c.b;
}

__device__ __forceinline__ int prefix_cnt(const int* cnt, int e) {
    int b = 0;
    for (int j = 0; j < NEXP; j++) b += (j < e) ? cnt[j] : 0;
    return b;
}

// ------------------------------------------------------------------ gate
__global__ __launch_bounds__(256) void gate_kernel(
    const float* __restrict__ x, const float* __restrict__ wg,
    int* __restrict__ cnt, int* __restrict__ tok, float* __restrict__ wgt,
    u16* __restrict__ xb)
{
    int t = blockIdx.x * 4 + (threadIdx.x >> 6);
    int lane = threadIdx.x & 63;
    float s[8];
#pragma unroll
    for (int e = 0; e < 8; e++) s[e] = 0.f;
    const float* xr = x + (size_t)t * DIMD;
    u16* xbr = xb + (size_t)t * DIMD;
#pragma unroll
    for (int i = 0; i < 16; i++) {
        int d = i * 64 + lane;
        float xv = xr[d];
        xbr[d] = f2bf(xv);
        float4 w0 = *(const float4*)(wg + d * 8);
        float4 w1 = *(const float4*)(wg + d * 8 + 4);
        s[0] += xv * w0.x; s[1] += xv * w0.y;
        s[2] += xv * w0.z; s[3] += xv * w0.w;
        s[4] += xv * w1.x; s[5] += xv * w1.y;
        s[6] += xv * w1.z; s[7] += xv * w1.w;
    }
#pragma unroll
    for (int e = 0; e < 8; e++)
        for (int off = 32; off; off >>= 1) s[e] += __shfl_xor(s[e], off, 64);
    if (lane == 0) {
        int e0 = 0; float b0 = s[0];
        for (int e = 1; e < 8; e++) if (s[e] > b0) { b0 = s[e]; e0 = e; }
        int e1 = (e0 == 0) ? 1 : 0; float b1 = s[e1];
        for (int e = 0; e < 8; e++) if (e != e0 && s[e] > b1) { b1 = s[e]; e1 = e; }
        float ex = __expf(b1 - b0);
        float w0 = 1.f / (1.f + ex);
        float w1 = ex / (1.f + ex);
        int p0 = atomicAdd(&cnt[e0], 1);
        tok[e0 * T_TOK + p0] = t; wgt[e0 * T_TOK + p0] = w0;
        int p1 = atomicAdd(&cnt[e1], 1);
        tok[e1 * T_TOK + p1] = t; wgt[e1 * T_TOK + p1] = w1;
    }
}

// ---------------------------------------------- token -> slot map
__global__ __launch_bounds__(256) void map_kernel(
    const int* __restrict__ cnt, const int* __restrict__ tok,
    int* __restrict__ tcnt, int* __restrict__ t2s)
{
    int gid = blockIdx.x * 256 + threadIdx.x;   // 0..32767
    int e = gid >> 12, i = gid & 4095;
    if (i >= cnt[e]) return;
    int base = prefix_cnt(cnt, e);
    int t = tok[e * T_TOK + i];
    int idx = atomicAdd(&tcnt[t], 1);
    t2s[2 * t + idx] = base + i;
}

// ------------------------------------- weight transpose + fp32->bf16 (all 3 fused)
// z<8: W1, z<16: W3 (K=1024,N=2048); z>=16: W2 (K=2048,N=1024)
__global__ __launch_bounds__(256) void transpose_kernel(
    const float* __restrict__ w1, u16* __restrict__ w1t,
    const float* __restrict__ w3, u16* __restrict__ w3t,
    const float* __restrict__ w2, u16* __restrict__ w2t)
{
    __shared__ u16 t[64 * 72];
    int z = blockIdx.z;
    int e = z & 7;
    const float* in; u16* out; int K, N;
    if (z < 16) {
        K = DIMD; N = HIDN;
        in = (z < 8) ? w1 : w3; out = (z < 8) ? w1t : w3t;
        if ((int)blockIdx.y >= K / 64) return;
    } else {
        K = HIDN; N = DIMD;
        in = w2; out = w2t;
        if ((int)blockIdx.x >= N / 64) return;
    }
    int n0 = blockIdx.x * 64, k0 = blockIdx.y * 64;
    const float* ip = in + (size_t)e * K * N;
    u16* op = out + (size_t)e * K * N;
    int tid = threadIdx.x;
    int r = tid >> 2, c = (tid & 3) * 16;
    const float4* src = (const float4*)(ip + (size_t)(k0 + r) * N + n0 + c);
    float4 v0 = src[0], v1 = src[1], v2 = src[2], v3 = src[3];
    u16* dstl = t + r * 72 + c;
    dstl[0]  = f2bf(v0.x); dstl[1]  = f2bf(v0.y); dstl[2]  = f2bf(v0.z); dstl[3]  = f2bf(v0.w);
    dstl[4]  = f2bf(v1.x); dstl[5]  = f2bf(v1.y); dstl[6]  = f2bf(v1.z); dstl[7]  = f2bf(v1.w);
    dstl[8]  = f2bf(v2.x); dstl[9]  = f2bf(v2.y); dstl[10] = f2bf(v2.z); dstl[11] = f2bf(v2.w);
    dstl[12] = f2bf(v3.x); dstl[13] = f2bf(v3.y); dstl[14] = f2bf(v3.z); dstl[15] = f2bf(v3.w);
    __syncthreads();
    int n = tid >> 2;
    union { u16 s[16]; uint4 q[2]; } u;
#pragma unroll
    for (int i = 0; i < 16; i++) u.s[i] = t[(c + i) * 72 + n];
    uint4* dst = (uint4*)(op + (size_t)(n0 + n) * K + k0 + c);
    dst[0] = u.q[0]; dst[1] = u.q[1];
}

// ------------------------------------------------------------------ GEMM1
// H[slot] = w * silu(x@W1) * (x@W3). Tile 128M x 64N x 64K.
// A (gathered token rows) read DIRECT from global into frags; B via LDS.
__global__ __launch_bounds__(256, 4) void gemm1_kernel(
    const u16* __restrict__ xb, const u16* __restrict__ w1t, const u16* __restrict__ w3t,
    const int* __restrict__ cnt, const int* __restrict__ tok,
    const float* __restrict__ wgt, u16* __restrict__ H)
{
    const int e = blockIdx.z, mt = blockIdx.y, nt = blockIdx.x;
    const int ce = cnt[e];
    if (mt * 128 >= ce) return;
    const int base = prefix_cnt(cnt, e);
    const int* tokp = tok + e * T_TOK;

    __shared__ u16 smem[64 * 64 * 2];
    u16* B1s = smem;
    u16* B2s = smem + 64 * 64;

    const int tid = threadIdx.x;
    const int lane = tid & 63, q = lane >> 4, ln = lane & 15;
    const int wv = tid >> 6;
    const int wm = (wv & 1) * 64, wn = (wv >> 1) * 32;
    const int wbase = tid & ~63;

    // A row pointers (token gather), one row per (mf, lane ln)
    const u16* arp[4];
#pragma unroll
    for (int mf = 0; mf < 4; mf++) {
        int mg = mt * 128 + wm + mf * 16 + ln;
        int tr = (mg < ce) ? tokp[mg] : 0;
        arp[mf] = xb + (size_t)tr * DIMD;
    }

    f32x4 acc1[4][2], acc2[4][2];
#pragma unroll
    for (int a = 0; a < 4; a++)
#pragma unroll
        for (int b = 0; b < 2; b++) { acc1[a][b] = {0.f,0.f,0.f,0.f}; acc2[a][b] = {0.f,0.f,0.f,0.f}; }

    const u16* w1p = w1t + ((size_t)e * HIDN + nt * 64) * DIMD;
    const u16* w3p = w3t + ((size_t)e * HIDN + nt * 64) * DIMD;

    for (int k0 = 0; k0 < DIMD; k0 += 64) {
        __syncthreads();
#pragma unroll
        for (int i = 0; i < 2; i++) {          // B tiles: 64 rows x 128B each
            int slot = i * 256 + tid;
            int n = slot >> 3;
            int bk = (slot & 7) ^ (n & 7);
            gl2lds16(w1p + (size_t)n * DIMD + k0 + bk * 8, B1s + (i * 256 + wbase) * 8);
            gl2lds16(w3p + (size_t)n * DIMD + k0 + bk * 8, B2s + (i * 256 + wbase) * 8);
        }
        __syncthreads();
#pragma unroll
        for (int s = 0; s < 2; s++) {
            bf16x8 af[4];
#pragma unroll
            for (int mf = 0; mf < 4; mf++) af[mf] = ldfragG(arp[mf], k0 + s * 32 + q * 8);
#pragma unroll
            for (int nf = 0; nf < 2; nf++) {
                bf16x8 b1 = ldfrag(B1s, wn + nf * 16 + ln, s, q);
                bf16x8 b2 = ldfrag(B2s, wn + nf * 16 + ln, s, q);
#pragma unroll
                for (int mf = 0; mf < 4; mf++) {
                    acc1[mf][nf] = __builtin_amdgcn_mfma_f32_16x16x32_bf16(af[mf], b1, acc1[mf][nf], 0, 0, 0);
                    acc2[mf][nf] = __builtin_amdgcn_mfma_f32_16x16x32_bf16(af[mf], b2, acc2[mf][nf], 0, 0, 0);
                }
            }
        }
    }

    const float* wr = wgt + e * T_TOK;
#pragma unroll
    for (int mf = 0; mf < 4; mf++) {
#pragma unroll
        for (int r = 0; r < 4; r++) {
            int mg = mt * 128 + wm + mf * 16 + q * 4 + r;
            if (mg < ce) {
                float wv_ = wr[mg];
                size_t hrow = (size_t)(base + mg) * HIDN + nt * 64 + wn;
#pragma unroll
                for (int nf = 0; nf < 2; nf++) {
                    float c1 = acc1[mf][nf][r], c2 = acc2[mf][nf][r];
                    float h = (c1 / (1.f + __expf(-c1))) * c2 * wv_;
                    H[hrow + nf * 16 + ln] = f2bf(h);
                }
            }
        }
    }
}

// ------------------------------------------------------------------ GEMM2
// O_slot[slot] = H[slot] @ W2. Tile 128M x 128N x 64K. No atomics.
// A (H rows) direct from global; B (W2) via LDS.
__global__ __launch_bounds__(256, 4) void gemm2_kernel(
    const u16* __restrict__ H, const u16* __restrict__ w2t,
    const int* __restrict__ cnt, float* __restrict__ os)
{
    const int e = blockIdx.z, mt = blockIdx.y, nt = blockIdx.x;
    const int ce = cnt[e];
    if (mt * 128 >= ce) return;
    const int base = prefix_cnt(cnt, e);

    __shared__ u16 Bs[128 * 64];

    const int tid = threadIdx.x;
    const int lane = tid & 63, q = lane >> 4, ln = lane & 15;
    const int wv = tid >> 6;
    const int wm = (wv & 1) * 64, wn = (wv >> 1) * 64;
    const int wbase = tid & ~63;

    const u16* arp[4];
#pragma unroll
    for (int mf = 0; mf < 4; mf++) {
        int mg = mt * 128 + wm + mf * 16 + ln;
        int sr = base + ((mg < ce) ? mg : 0);
        arp[mf] = H + (size_t)sr * HIDN;
    }

    f32x4 av[4][4];
#pragma unroll
    for (int a = 0; a < 4; a++)
#pragma unroll
        for (int b = 0; b < 4; b++) av[a][b] = {0.f,0.f,0.f,0.f};

    const u16* w2p = w2t + ((size_t)e * DIMD + nt * 128) * HIDN;

    for (int k0 = 0; k0 < HIDN; k0 += 64) {
        __syncthreads();
#pragma unroll
        for (int i = 0; i < 4; i++) {          // B tile: 128 rows x 128B
            int slot = i * 256 + tid;
            int m = slot >> 3;
            int bk = (slot & 7) ^ (m & 7);
            gl2lds16(w2p + (size_t)m * HIDN + k0 + bk * 8, Bs + (i * 256 + wbase) * 8);
        }
        __syncthreads();
#pragma unroll
        for (int s = 0; s < 2; s++) {
            bf16x8 af[4], bfr[4];
#pragma unroll
            for (int mf = 0; mf < 4; mf++) af[mf]  = ldfragG(arp[mf], k0 + s * 32 + q * 8);
#pragma unroll
            for (int nf = 0; nf < 4; nf++) bfr[nf] = ldfrag(Bs, wn + nf * 16 + ln, s, q);
#pragma unroll
            for (int mf = 0; mf < 4; mf++)
#pragma unroll
                for (int nf = 0; nf < 4; nf++)
                    av[mf][nf] = __builtin_amdgcn_mfma_f32_16x16x32_bf16(af[mf], bfr[nf], av[mf][nf], 0, 0, 0);
        }
    }

#pragma unroll
    for (int mf = 0; mf < 4; mf++) {
#pragma unroll
        for (int r = 0; r < 4; r++) {
            int mg = mt * 128 + wm + mf * 16 + q * 4 + r;
            if (mg < ce) {
                float* orow = os + (size_t)(base + mg) * DIMD + nt * 128 + wn;
#pragma unroll
                for (int nf = 0; nf < 4; nf++)
                    orow[nf * 16 + ln] = av[mf][nf][r];
            }
        }
    }
}

// --------------------------------------------------------------- reduce
// out[t] = O_slot[s0] + O_slot[s1]
__global__ __launch_bounds__(256) void reduce_kernel(
    const float* __restrict__ os, const int* __restrict__ t2s,
    float* __restrict__ out)
{
    int t = blockIdx.x;
    int s0 = t2s[2 * t], s1 = t2s[2 * t + 1];
    int c = threadIdx.x * 4;
    const float4* a = (const float4*)(os + (size_t)s0 * DIMD + c);
    const float4* b = (const float4*)(os + (size_t)s1 * DIMD + c);
    float4 va = *a, vb = *b;
    float4 o; o.x = va.x + vb.x; o.y = va.y + vb.y; o.z = va.z + vb.z; o.w = va.w + vb.w;
    *(float4*)(out + (size_t)t * DIMD + c) = o;
}

// ------------------------------------------------------------------ launch
extern "C" void kernel_launch(void* const* d_in, const int* in_sizes, int n_in,
                              void* d_out, int out_size, void* d_ws, size_t ws_size,
                              hipStream_t stream)
{
    const float* x  = (const float*)d_in[0];
    const float* wg = (const float*)d_in[1];
    const float* w1 = (const float*)d_in[2];
    const float* w3 = (const float*)d_in[3];
    const float* w2 = (const float*)d_in[4];

    char* ws = (char*)d_ws;
    int*   cnt  = (int*)(ws + OFF_CNT);
    int*   tcnt = (int*)(ws + OFF_TCNT);
    int*   tok  = (int*)(ws + OFF_TOK);
    float* wgt  = (float*)(ws + OFF_WGT);
    int*   t2s  = (int*)(ws + OFF_T2S);
    u16*   xb   = (u16*)(ws + OFF_XB);
    u16*   w1t  = (u16*)(ws + OFF_W1T);
    u16*   w3t  = (u16*)(ws + OFF_W3T);
    u16*   w2t  = (u16*)(ws + OFF_W2T);
    u16*   Hbuf = (u16*)(ws + OFF_H);
    float* osb  = (float*)(ws + OFF_OS);   // aliases w1t (dead after gemm1)
    float* outp = (float*)d_out;

    hipMemsetAsync(ws, 0, 64 + T_TOK * 4, stream);   // cnt + tcnt

    gate_kernel<<<T_TOK / 4, 256, 0, stream>>>(x, wg, cnt, tok, wgt, xb);
    map_kernel<<<(NEXP * T_TOK) / 256, 256, 0, stream>>>(cnt, tok, tcnt, t2s);

    transpose_kernel<<<dim3(32, 32, 24), 256, 0, stream>>>(w1, w1t, w3, w3t, w2, w2t);

    gemm1_kernel<<<dim3(HIDN / 64, T_TOK / 128, NEXP), 256, 0, stream>>>(
        xb, w1t, w3t, cnt, tok, wgt, Hbuf);
    gemm2_kernel<<<dim3(DIMD / 128, T_TOK / 128, NEXP), 256, 0, stream>>>(
        Hbuf, w2t, cnt, osb);

    reduce_kernel<<<T_TOK, 256, 0, stream>>>(osb, t2s, outp);
}

// Round 5
// 506.785 us; speedup vs baseline: 1.2563x; 1.2563x over previous
//
#include <hip/hip_runtime.h>

typedef unsigned short u16;
typedef unsigned int u32;
using bf16x8 = __attribute__((ext_vector_type(8))) __bf16;
using f32x4  = __attribute__((ext_vector_type(4))) float;

#define T_TOK 4096
#define DIMD  1024
#define HIDN  2048
#define NEXP  8
#define NSLOT (2 * T_TOK)

// ---- workspace layout (bytes) ----
#define OFF_CNT  0                            // int[8]
#define OFF_TCNT 64                           // int[4096]
#define OFF_TOK  16448                        // int[8][4096]
#define OFF_WGT  (OFF_TOK + NEXP*T_TOK*4)     // float[8][4096]
#define OFF_T2S  (OFF_WGT + NEXP*T_TOK*4)     // int[4096][2]
#define OFF_XB   (1<<20)                      // bf16[4096][1024]
#define SZ_XB    (T_TOK*DIMD*2)
#define OFF_W1T  (OFF_XB + SZ_XB)             // bf16 [E][N][K]
#define SZ_W     (NEXP*DIMD*HIDN*2)           // 32 MB each
#define OFF_W3T  (OFF_W1T + SZ_W)
#define OFF_W2T  (OFF_W3T + SZ_W)
#define OFF_H    (OFF_W2T + SZ_W)             // bf16[8192][2048]
#define OFF_OS   OFF_W1T                      // fp32[2][8192][1024] ALIASES W1T+W3T (dead after gemm1)

__device__ __forceinline__ u16 f2bf(float f) {
    u32 u = __float_as_uint(f);
    u32 r = (u + 0x7fff + ((u >> 16) & 1)) >> 16;
    return (u16)r;
}

__device__ __forceinline__ void gl2lds16(const void* g, void* l) {
    __builtin_amdgcn_global_load_lds(
        (__attribute__((address_space(1))) void*)(g),
        (__attribute__((address_space(3))) void*)(l),
        16, 0, 0);
}

// swizzled LDS frag read (tile rows of 64 bf16; 16B-block b of row r stored at b ^ (r&7))
__device__ __forceinline__ bf16x8 ldfrag(const u16* base, int r, int s, int q) {
    int idx = r * 64 + ((((s << 2) | q) ^ (r & 7)) << 3);
    union { uint4 u; bf16x8 b; } c;
    c.u = *(const uint4*)(base + idx);
    return c.b;
}

__device__ __forceinline__ int prefix_cnt(const int* cnt, int e) {
    int b = 0;
#pragma unroll
    for (int j = 0; j < NEXP; j++) b += (j < e) ? cnt[j] : 0;
    return b;
}

// ------------------------------------------------------------------ gate
__global__ __launch_bounds__(256) void gate_kernel(
    const float* __restrict__ x, const float* __restrict__ wg,
    int* __restrict__ cnt, int* __restrict__ tok, float* __restrict__ wgt,
    u16* __restrict__ xb)
{
    int t = blockIdx.x * 4 + (threadIdx.x >> 6);
    int lane = threadIdx.x & 63;
    float s[8];
#pragma unroll
    for (int e = 0; e < 8; e++) s[e] = 0.f;
    const float* xr = x + (size_t)t * DIMD;
    u16* xbr = xb + (size_t)t * DIMD;
#pragma unroll
    for (int i = 0; i < 16; i++) {
        int d = i * 64 + lane;
        float xv = xr[d];
        xbr[d] = f2bf(xv);
        float4 w0 = *(const float4*)(wg + d * 8);
        float4 w1 = *(const float4*)(wg + d * 8 + 4);
        s[0] += xv * w0.x; s[1] += xv * w0.y;
        s[2] += xv * w0.z; s[3] += xv * w0.w;
        s[4] += xv * w1.x; s[5] += xv * w1.y;
        s[6] += xv * w1.z; s[7] += xv * w1.w;
    }
#pragma unroll
    for (int e = 0; e < 8; e++)
        for (int off = 32; off; off >>= 1) s[e] += __shfl_xor(s[e], off, 64);
    if (lane == 0) {
        int e0 = 0; float b0 = s[0];
        for (int e = 1; e < 8; e++) if (s[e] > b0) { b0 = s[e]; e0 = e; }
        int e1 = (e0 == 0) ? 1 : 0; float b1 = s[e1];
        for (int e = 0; e < 8; e++) if (e != e0 && s[e] > b1) { b1 = s[e]; e1 = e; }
        float ex = __expf(b1 - b0);
        float w0 = 1.f / (1.f + ex);
        float w1 = ex / (1.f + ex);
        int p0 = atomicAdd(&cnt[e0], 1);
        tok[e0 * T_TOK + p0] = t; wgt[e0 * T_TOK + p0] = w0;
        int p1 = atomicAdd(&cnt[e1], 1);
        tok[e1 * T_TOK + p1] = t; wgt[e1 * T_TOK + p1] = w1;
    }
}

// ---------------------------------------------- token -> slot map
__global__ __launch_bounds__(256) void map_kernel(
    const int* __restrict__ cnt, const int* __restrict__ tok,
    int* __restrict__ tcnt, int* __restrict__ t2s)
{
    int gid = blockIdx.x * 256 + threadIdx.x;
    int e = gid >> 12, i = gid & 4095;
    if (i >= cnt[e]) return;
    int base = prefix_cnt(cnt, e);
    int t = tok[e * T_TOK + i];
    int idx = atomicAdd(&tcnt[t], 1);
    t2s[2 * t + idx] = base + i;
}

// ------------------------------------- weight transpose + fp32->bf16
// fp32 [K][N] tile staged to LDS via global_load_lds (no VALU LDS writes),
// conflict-free b32 column reads, coalesced bf16 row writes.
__global__ __launch_bounds__(256) void wtr_kernel(
    const float* __restrict__ w1, u16* __restrict__ w1t,
    const float* __restrict__ w3, u16* __restrict__ w3t,
    const float* __restrict__ w2, u16* __restrict__ w2t)
{
    __shared__ float Lf[64 * 64];   // 16 KB, natural [k][n]
    int bid = blockIdx.x;
    int tz = bid >> 9;              // 0..23
    int tt = bid & 511;
    int e = tz & 7;
    const float* in; u16* out; int K, N, kt, ntl;
    if (tz < 16) {
        in = (tz < 8) ? w1 : w3; out = (tz < 8) ? w1t : w3t;
        K = DIMD; N = HIDN; kt = tt >> 5; ntl = tt & 31;
    } else {
        in = w2; out = w2t;
        K = HIDN; N = DIMD; kt = tt >> 4; ntl = tt & 15;
    }
    int k0 = kt * 64, n0 = ntl * 64;
    const float* ip = in + (size_t)e * K * N;
    u16* op = out + (size_t)e * K * N;

    int tid = threadIdx.x;
    int wbase = tid & ~63;
#pragma unroll
    for (int i = 0; i < 4; i++) {
        int slot = i * 256 + tid;
        int r = slot >> 4, cb = slot & 15;     // row k-local, 16B col-block
        gl2lds16(ip + (size_t)(k0 + r) * N + n0 + cb * 4,
                 Lf + (i * 256 + wbase) * 4);
    }
    __syncthreads();

    int w = tid >> 6, lane = tid & 63;         // wave w: k-slice, lane: n
    union { u16 s[16]; uint4 q[2]; } u;
#pragma unroll
    for (int i = 0; i < 16; i++)
        u.s[i] = f2bf(Lf[(w * 16 + i) * 64 + lane]);   // bank = lane%32: 2-way, free
    uint4* dst = (uint4*)(op + (size_t)(n0 + lane) * K + k0 + w * 16);
    dst[0] = u.q[0]; dst[1] = u.q[1];
}

// ------------------------------------------------------------------ GEMM1
// Tile 128M x (64 W1-cols || 64 W3-cols) x 64K. Waves 0,1: x@W1; waves 2,3: x@W3.
// Epilogue: exchange W3 acc via LDS, H = wgt * silu(c1) * c2.
__global__ __launch_bounds__(256, 3) void gemm1_kernel(
    const u16* __restrict__ xb, const u16* __restrict__ w1t, const u16* __restrict__ w3t,
    const int* __restrict__ cnt, const int* __restrict__ tok,
    const float* __restrict__ wgt, u16* __restrict__ H)
{
    const int e = blockIdx.z, mt = blockIdx.y, nt = blockIdx.x;
    const int ce = cnt[e];
    if (mt * 128 >= ce) return;
    const int base = prefix_cnt(cnt, e);
    const int* tokp = tok + e * T_TOK;

    __shared__ u16 smem[128 * 64 + 64 * 64 + 64 * 64];   // 32 KB
    u16* As  = smem;
    u16* B1s = smem + 128 * 64;
    u16* B3s = B1s + 64 * 64;

    const int tid = threadIdx.x;
    const int lane = tid & 63, q = lane >> 4, ln = lane & 15;
    const int wv = tid >> 6;
    const int wm = (wv & 1) * 64;
    const int wsel = wv >> 1;              // 0: W1 product, 1: W3 product
    const int wbase = tid & ~63;

    // hoisted k-invariant staging addresses
    const u16* arow[4];
#pragma unroll
    for (int i = 0; i < 4; i++) {
        int slot = i * 256 + tid;
        int m = slot >> 3;
        int bk = (slot & 7) ^ (m & 7);
        int mg = mt * 128 + m;
        int tr = (mg < ce) ? tokp[mg] : 0;
        arow[i] = xb + (size_t)tr * DIMD + bk * 8;
    }
    const u16* w1p = w1t + ((size_t)e * HIDN + nt * 64) * DIMD;
    const u16* w3p = w3t + ((size_t)e * HIDN + nt * 64) * DIMD;
    const u16* b1row[2]; const u16* b3row[2];
#pragma unroll
    for (int i = 0; i < 2; i++) {
        int slot = i * 256 + tid;
        int n = slot >> 3;
        int bk = (slot & 7) ^ (n & 7);
        b1row[i] = w1p + (size_t)n * DIMD + bk * 8;
        b3row[i] = w3p + (size_t)n * DIMD + bk * 8;
    }

    f32x4 acc[4][4];
#pragma unroll
    for (int a = 0; a < 4; a++)
#pragma unroll
        for (int b = 0; b < 4; b++) acc[a][b] = {0.f, 0.f, 0.f, 0.f};

    const u16* Bsel = wsel ? B3s : B1s;

    for (int k0 = 0; k0 < DIMD; k0 += 64) {
        __syncthreads();
#pragma unroll
        for (int i = 0; i < 4; i++)
            gl2lds16(arow[i] + k0, As + (i * 256 + wbase) * 8);
#pragma unroll
        for (int i = 0; i < 2; i++) {
            gl2lds16(b1row[i] + k0, B1s + (i * 256 + wbase) * 8);
            gl2lds16(b3row[i] + k0, B3s + (i * 256 + wbase) * 8);
        }
        __syncthreads();
#pragma unroll
        for (int s = 0; s < 2; s++) {
            bf16x8 af[4], bf[4];
#pragma unroll
            for (int mf = 0; mf < 4; mf++) af[mf] = ldfrag(As, wm + mf * 16 + ln, s, q);
#pragma unroll
            for (int nf = 0; nf < 4; nf++) bf[nf] = ldfrag(Bsel, nf * 16 + ln, s, q);
#pragma unroll
            for (int mf = 0; mf < 4; mf++)
#pragma unroll
                for (int nf = 0; nf < 4; nf++)
                    acc[mf][nf] = __builtin_amdgcn_mfma_f32_16x16x32_bf16(af[mf], bf[nf], acc[mf][nf], 0, 0, 0);
        }
    }

    // epilogue: W3 waves export acc; W1 waves combine + write H
    __syncthreads();
    float* ex = (float*)smem;                  // 32 KB = 2 x 16 KB regions
    const int pj = wv & 1;
    if (wsel == 1) {
#pragma unroll
        for (int mf = 0; mf < 4; mf++)
#pragma unroll
            for (int nf = 0; nf < 4; nf++)
                *(f32x4*)(ex + pj * 4096 + ((mf * 4 + nf) * 64 + lane) * 4) = acc[mf][nf];
    }
    __syncthreads();
    if (wsel == 0) {
        const float* wr = wgt + e * T_TOK;
#pragma unroll
        for (int mf = 0; mf < 4; mf++) {
#pragma unroll
            for (int nf = 0; nf < 4; nf++) {
                f32x4 c2 = *(const f32x4*)(ex + pj * 4096 + ((mf * 4 + nf) * 64 + lane) * 4);
#pragma unroll
                for (int r = 0; r < 4; r++) {
                    int mg = mt * 128 + wm + mf * 16 + q * 4 + r;
                    if (mg < ce) {
                        float c1 = acc[mf][nf][r];
                        float h = (c1 / (1.f + __expf(-c1))) * c2[r] * wr[mg];
                        H[(size_t)(base + mg) * HIDN + nt * 64 + nf * 16 + ln] = f2bf(h);
                    }
                }
            }
        }
    }
}

// ------------------------------------------------------------------ GEMM2
// os[kh][slot] = H[slot] @ W2 (K-half kh). Tile 128M x 128N x 64K, m97 structure.
__global__ __launch_bounds__(256, 3) void gemm2_kernel(
    const u16* __restrict__ H, const u16* __restrict__ w2t,
    const int* __restrict__ cnt, float* __restrict__ os)
{
    const int e = blockIdx.z & 7, kh = blockIdx.z >> 3;
    const int mt = blockIdx.y, nt = blockIdx.x;
    const int ce = cnt[e];
    if (mt * 128 >= ce) return;
    const int base = prefix_cnt(cnt, e);

    __shared__ u16 smem[128 * 64 * 2];   // 32 KB
    u16* As = smem;
    u16* Bs = smem + 128 * 64;

    const int tid = threadIdx.x;
    const int lane = tid & 63, q = lane >> 4, ln = lane & 15;
    const int wv = tid >> 6;
    const int wm = (wv & 1) * 64, wn = (wv >> 1) * 64;
    const int wbase = tid & ~63;

    const u16* arow[4];
    const u16* brow[4];
    const u16* w2p = w2t + ((size_t)e * DIMD + nt * 128) * HIDN;
#pragma unroll
    for (int i = 0; i < 4; i++) {
        int slot = i * 256 + tid;
        int m = slot >> 3;
        int bk = (slot & 7) ^ (m & 7);
        int mg = mt * 128 + m;
        int ar = base + ((mg < ce) ? mg : 0);
        arow[i] = H + (size_t)ar * HIDN + bk * 8;
        brow[i] = w2p + (size_t)m * HIDN + bk * 8;
    }

    f32x4 acc[4][4];
#pragma unroll
    for (int a = 0; a < 4; a++)
#pragma unroll
        for (int b = 0; b < 4; b++) acc[a][b] = {0.f, 0.f, 0.f, 0.f};

    const int kbeg = kh * (HIDN / 2), kend = kbeg + HIDN / 2;
    for (int k0 = kbeg; k0 < kend; k0 += 64) {
        __syncthreads();
#pragma unroll
        for (int i = 0; i < 4; i++) {
            gl2lds16(arow[i] + k0, As + (i * 256 + wbase) * 8);
            gl2lds16(brow[i] + k0, Bs + (i * 256 + wbase) * 8);
        }
        __syncthreads();
#pragma unroll
        for (int s = 0; s < 2; s++) {
            bf16x8 af[4], bf[4];
#pragma unroll
            for (int mf = 0; mf < 4; mf++) af[mf] = ldfrag(As, wm + mf * 16 + ln, s, q);
#pragma unroll
            for (int nf = 0; nf < 4; nf++) bf[nf] = ldfrag(Bs, wn + nf * 16 + ln, s, q);
#pragma unroll
            for (int mf = 0; mf < 4; mf++)
#pragma unroll
                for (int nf = 0; nf < 4; nf++)
                    acc[mf][nf] = __builtin_amdgcn_mfma_f32_16x16x32_bf16(af[mf], bf[nf], acc[mf][nf], 0, 0, 0);
        }
    }

    float* osk = os + (size_t)kh * NSLOT * DIMD;
#pragma unroll
    for (int mf = 0; mf < 4; mf++) {
#pragma unroll
        for (int r = 0; r < 4; r++) {
            int mg = mt * 128 + wm + mf * 16 + q * 4 + r;
            if (mg < ce) {
                float* orow = osk + (size_t)(base + mg) * DIMD + nt * 128 + wn;
#pragma unroll
                for (int nf = 0; nf < 4; nf++)
                    orow[nf * 16 + ln] = acc[mf][nf][r];
            }
        }
    }
}

// --------------------------------------------------------------- reduce
// out[t] = sum over 2 slots x 2 k-halves
__global__ __launch_bounds__(256) void reduce_kernel(
    const float* __restrict__ os, const int* __restrict__ t2s,
    float* __restrict__ out)
{
    int t = blockIdx.x;
    int s0 = t2s[2 * t], s1 = t2s[2 * t + 1];
    int c = threadIdx.x * 4;
    const size_t khs = (size_t)NSLOT * DIMD;
    float4 a0 = *(const float4*)(os + (size_t)s0 * DIMD + c);
    float4 a1 = *(const float4*)(os + (size_t)s1 * DIMD + c);
    float4 b0 = *(const float4*)(os + khs + (size_t)s0 * DIMD + c);
    float4 b1 = *(const float4*)(os + khs + (size_t)s1 * DIMD + c);
    float4 o;
    o.x = (a0.x + a1.x) + (b0.x + b1.x);
    o.y = (a0.y + a1.y) + (b0.y + b1.y);
    o.z = (a0.z + a1.z) + (b0.z + b1.z);
    o.w = (a0.w + a1.w) + (b0.w + b1.w);
    *(float4*)(out + (size_t)t * DIMD + c) = o;
}

// ------------------------------------------------------------------ launch
extern "C" void kernel_launch(void* const* d_in, const int* in_sizes, int n_in,
                              void* d_out, int out_size, void* d_ws, size_t ws_size,
                              hipStream_t stream)
{
    const float* x  = (const float*)d_in[0];
    const float* wg = (const float*)d_in[1];
    const float* w1 = (const float*)d_in[2];
    const float* w3 = (const float*)d_in[3];
    const float* w2 = (const float*)d_in[4];

    char* ws = (char*)d_ws;
    int*   cnt  = (int*)(ws + OFF_CNT);
    int*   tcnt = (int*)(ws + OFF_TCNT);
    int*   tok  = (int*)(ws + OFF_TOK);
    float* wgt  = (float*)(ws + OFF_WGT);
    int*   t2s  = (int*)(ws + OFF_T2S);
    u16*   xb   = (u16*)(ws + OFF_XB);
    u16*   w1t  = (u16*)(ws + OFF_W1T);
    u16*   w3t  = (u16*)(ws + OFF_W3T);
    u16*   w2t  = (u16*)(ws + OFF_W2T);
    u16*   Hbuf = (u16*)(ws + OFF_H);
    float* osb  = (float*)(ws + OFF_OS);   // aliases w1t/w3t (dead after gemm1)
    float* outp = (float*)d_out;

    hipMemsetAsync(ws, 0, 64 + T_TOK * 4, stream);   // cnt + tcnt

    gate_kernel<<<T_TOK / 4, 256, 0, stream>>>(x, wg, cnt, tok, wgt, xb);
    map_kernel<<<(NEXP * T_TOK) / 256, 256, 0, stream>>>(cnt, tok, tcnt, t2s);

    wtr_kernel<<<24 * 512, 256, 0, stream>>>(w1, w1t, w3, w3t, w2, w2t);

    gemm1_kernel<<<dim3(HIDN / 64, T_TOK / 128, NEXP), 256, 0, stream>>>(
        xb, w1t, w3t, cnt, tok, wgt, Hbuf);
    gemm2_kernel<<<dim3(DIMD / 128, T_TOK / 128, NEXP * 2), 256, 0, stream>>>(
        Hbuf, w2t, cnt, osb);

    reduce_kernel<<<T_TOK, 256, 0, stream>>>(osb, t2s, outp);
}